// Round 7
// baseline (331.189 us; speedup 1.0000x reference)
//
#include <hip/hip_runtime.h>
#include <math.h>

#define NN 4096
#define DIMV 256
#define ECAP 768   // max edges/row; Binomial(4096,0.05): mean 205, sd 14 (40 sigma)

typedef float f32x4 __attribute__((ext_vector_type(4)));

// ---------------------------------------------------------------------------
// QKV GEMM: C = x @ W^T + bias.  Tile 64(M)x128(N), BK=32, 256 threads,
// 8x4 microtile. z-block 2 (V) also accumulates column sums into S (atomics).
// ---------------------------------------------------------------------------
__global__ __launch_bounds__(256) void qkv_gemm(
    const float* __restrict__ x,
    const float* __restrict__ Wq, const float* __restrict__ Wk, const float* __restrict__ Wv,
    const float* __restrict__ bq, const float* __restrict__ bk, const float* __restrict__ bv,
    float* __restrict__ Q, float* __restrict__ K, float* __restrict__ V,
    float* __restrict__ S)
{
    __shared__ float As[32][69];    // [k][row]
    __shared__ float Bs[32][133];   // [k][col]

    const int which = blockIdx.z;
    const float* __restrict__ W = which == 0 ? Wq : (which == 1 ? Wk : Wv);
    const float* __restrict__ bias = which == 0 ? bq : (which == 1 ? bk : bv);
    float* __restrict__ C = which == 0 ? Q : (which == 1 ? K : V);

    const int tid = threadIdx.x;
    const int row0 = blockIdx.x * 64, col0 = blockIdx.y * 128;
    const int ty = tid >> 5;          // 0..7  -> rows ty*8..+7
    const int tx = tid & 31;          // 0..31 -> cols tx*4..+3
    const int lrA = tid >> 2;         // 0..63 row
    const int lcA = (tid & 3) * 8;    // k offset 0,8,16,24
    const int lrB = tid >> 1;         // 0..127 col
    const int lcB = (tid & 1) * 16;   // k offset 0,16

    float acc[8][4] = {};

    for (int k0 = 0; k0 < 256; k0 += 32) {
        const float4 a0 = *(const float4*)(x + (size_t)(row0 + lrA) * 256 + k0 + lcA);
        const float4 a1 = *(const float4*)(x + (size_t)(row0 + lrA) * 256 + k0 + lcA + 4);
        const float4 b0 = *(const float4*)(W + (size_t)(col0 + lrB) * 256 + k0 + lcB);
        const float4 b1 = *(const float4*)(W + (size_t)(col0 + lrB) * 256 + k0 + lcB + 4);
        const float4 b2 = *(const float4*)(W + (size_t)(col0 + lrB) * 256 + k0 + lcB + 8);
        const float4 b3 = *(const float4*)(W + (size_t)(col0 + lrB) * 256 + k0 + lcB + 12);
        __syncthreads();
        As[lcA + 0][lrA] = a0.x; As[lcA + 1][lrA] = a0.y; As[lcA + 2][lrA] = a0.z; As[lcA + 3][lrA] = a0.w;
        As[lcA + 4][lrA] = a1.x; As[lcA + 5][lrA] = a1.y; As[lcA + 6][lrA] = a1.z; As[lcA + 7][lrA] = a1.w;
        Bs[lcB +  0][lrB] = b0.x; Bs[lcB +  1][lrB] = b0.y; Bs[lcB +  2][lrB] = b0.z; Bs[lcB +  3][lrB] = b0.w;
        Bs[lcB +  4][lrB] = b1.x; Bs[lcB +  5][lrB] = b1.y; Bs[lcB +  6][lrB] = b1.z; Bs[lcB +  7][lrB] = b1.w;
        Bs[lcB +  8][lrB] = b2.x; Bs[lcB +  9][lrB] = b2.y; Bs[lcB + 10][lrB] = b2.z; Bs[lcB + 11][lrB] = b2.w;
        Bs[lcB + 12][lrB] = b3.x; Bs[lcB + 13][lrB] = b3.y; Bs[lcB + 14][lrB] = b3.z; Bs[lcB + 15][lrB] = b3.w;
        __syncthreads();
#pragma unroll
        for (int kk = 0; kk < 32; kk++) {
            const float4 alo = *(const float4*)&As[kk][ty * 8];
            const float4 ahi = *(const float4*)&As[kk][ty * 8 + 4];
            const float4 bv4 = *(const float4*)&Bs[kk][tx * 4];
            const float av[8] = {alo.x, alo.y, alo.z, alo.w, ahi.x, ahi.y, ahi.z, ahi.w};
            const float bw[4] = {bv4.x, bv4.y, bv4.z, bv4.w};
#pragma unroll
            for (int r = 0; r < 8; r++)
#pragma unroll
                for (int c = 0; c < 4; c++)
                    acc[r][c] = fmaf(av[r], bw[c], acc[r][c]);
        }
    }

    const int gc = col0 + tx * 4;
    const float4 b4 = *(const float4*)(bias + gc);
    float cs0 = 0.f, cs1 = 0.f, cs2 = 0.f, cs3 = 0.f;
#pragma unroll
    for (int r = 0; r < 8; r++) {
        const int gr = row0 + ty * 8 + r;
        float4 v;
        v.x = acc[r][0] + b4.x; v.y = acc[r][1] + b4.y;
        v.z = acc[r][2] + b4.z; v.w = acc[r][3] + b4.w;
        *(float4*)(C + (size_t)gr * 256 + gc) = v;
        cs0 += v.x; cs1 += v.y; cs2 += v.z; cs3 += v.w;
    }
    if (which == 2) {   // V blocks: accumulate column sums
        atomicAdd(&S[gc + 0], cs0);
        atomicAdd(&S[gc + 1], cs1);
        atomicAdd(&S[gc + 2], cs2);
        atomicAdd(&S[gc + 3], cs3);
    }
}

// ---------------------------------------------------------------------------
// Fused sparse attention, two-phase. One block (512 thr, 8 waves) per row i.
//  A: nontemporal adj scan, deterministic cross-wave scan compaction -> lj[]
//     (globally j-sorted: wave w covers cols [w*512,(w+1)*512))
//  B: QK scores: wave-per-edge, 4-edge ILP, coalesced 1KB K-row per edge,
//     16-lane shfl reduce per head, w = expf(s)-1 -> wgt[e][h] in LDS
//  C: PV: 2 dim-groups x 256 dims, 8-way unrolled coalesced V-row loads
//  D: out = (num + S) / (den + 4096)
// ---------------------------------------------------------------------------
__global__ __launch_bounds__(512, 4) void attn_v3(
    const float* __restrict__ Q, const float* __restrict__ K,
    const float* __restrict__ V, const float* __restrict__ adj,
    const float* __restrict__ S, float* __restrict__ out)
{
    __shared__ unsigned short lj[ECAP];
    __shared__ float wgt[ECAP * 4];
    __shared__ float pnum[2][256];
    __shared__ float pden[2][4];
    __shared__ int wtot[8], wbase[8], cnt;

    const int i = blockIdx.x;
    const int tid = threadIdx.x;
    const int wave = tid >> 6;
    const int lane = tid & 63;

    // ---- stage A: compact adjacency row (8 cols/thread, nontemporal) ----
    const f32x4* __restrict__ arow = (const f32x4*)(adj + (size_t)i * NN);
    const f32x4 a0 = __builtin_nontemporal_load(arow + 2 * tid);
    const f32x4 a1 = __builtin_nontemporal_load(arow + 2 * tid + 1);
    const int c = (a0.x != 0.f) + (a0.y != 0.f) + (a0.z != 0.f) + (a0.w != 0.f)
                + (a1.x != 0.f) + (a1.y != 0.f) + (a1.z != 0.f) + (a1.w != 0.f);
    int incl = c;
#pragma unroll
    for (int s = 1; s < 64; s <<= 1) {
        const int v = __shfl_up(incl, s);
        if (lane >= s) incl += v;
    }
    if (lane == 63) wtot[wave] = incl;
    __syncthreads();
    if (tid == 0) {
        int s = 0;
#pragma unroll
        for (int w = 0; w < 8; w++) { wbase[w] = s; s += wtot[w]; }
        cnt = s;
    }
    __syncthreads();
    {
        int p = wbase[wave] + incl - c;
        const int j0 = tid * 8;
        if (a0.x != 0.f && p < ECAP) lj[p++] = (unsigned short)(j0 + 0);
        if (a0.y != 0.f && p < ECAP) lj[p++] = (unsigned short)(j0 + 1);
        if (a0.z != 0.f && p < ECAP) lj[p++] = (unsigned short)(j0 + 2);
        if (a0.w != 0.f && p < ECAP) lj[p++] = (unsigned short)(j0 + 3);
        if (a1.x != 0.f && p < ECAP) lj[p++] = (unsigned short)(j0 + 4);
        if (a1.y != 0.f && p < ECAP) lj[p++] = (unsigned short)(j0 + 5);
        if (a1.z != 0.f && p < ECAP) lj[p++] = (unsigned short)(j0 + 6);
        if (a1.w != 0.f && p < ECAP) lj[p++] = (unsigned short)(j0 + 7);
    }
    __syncthreads();
    const int m = min(cnt, ECAP);

    // ---- stage B: QK scores ----
    const float4 qraw = ((const float4*)(Q + (size_t)i * 256))[lane];
    const float4 qv = {qraw.x * 0.125f, qraw.y * 0.125f, qraw.z * 0.125f, qraw.w * 0.125f};
    for (int e0 = wave * 4; e0 < m; e0 += 32) {
        int jj[4];
#pragma unroll
        for (int u = 0; u < 4; u++)
            jj[u] = (e0 + u < m) ? (int)lj[e0 + u] : (int)lj[e0];
        float4 kv[4];
#pragma unroll
        for (int u = 0; u < 4; u++)
            kv[u] = ((const float4*)(K + (size_t)jj[u] * 256))[lane];
#pragma unroll
        for (int u = 0; u < 4; u++) {
            float d = (kv[u].x * qv.x + kv[u].y * qv.y) + (kv[u].z * qv.z + kv[u].w * qv.w);
            d += __shfl_xor(d, 1);
            d += __shfl_xor(d, 2);
            d += __shfl_xor(d, 4);
            d += __shfl_xor(d, 8);
            if ((lane & 15) == 0 && e0 + u < m)
                wgt[(e0 + u) * 4 + (lane >> 4)] = expf(d) - 1.f;
        }
    }
    __syncthreads();

    // ---- stage C: PV ----
    const int g = tid >> 8;        // 0 or 1
    const int d = tid & 255;
    const int head = d >> 6;
    float num = 0.f, den = 0.f;
    int e = g;
    for (; e + 14 < m; e += 16) {
        float w[8];
#pragma unroll
        for (int u = 0; u < 8; u++) w[u] = wgt[(e + 2 * u) * 4 + head];
        float v[8];
#pragma unroll
        for (int u = 0; u < 8; u++)
            v[u] = V[(size_t)lj[e + 2 * u] * 256 + d];
#pragma unroll
        for (int u = 0; u < 8; u++) { num = fmaf(w[u], v[u], num); den += w[u]; }
    }
    for (; e < m; e += 2) {
        const float w = wgt[e * 4 + head];
        num = fmaf(w, V[(size_t)lj[e] * 256 + d], num);
        den += w;
    }
    pnum[g][d] = num;
    if ((d & 63) == 0) pden[g][head] = den;
    __syncthreads();

    // ---- stage D: output ----
    if (tid < 256) {
        const int h = tid >> 6;
        const float dn = pden[0][h] + pden[1][h] + 4096.0f;
        out[(size_t)i * 256 + tid] = (pnum[0][tid] + pnum[1][tid] + S[tid]) / dn;
    }
}

// ---------------------------------------------------------------------------
// Fused out-projection + residual + LayerNorm.
// Tile 16(M) x 256(N full width), BK=16, 256 threads, 4x4 microtile.
// Wave w owns rows w*4..w*4+3 -> in-register LN via shfl reduce.
// ---------------------------------------------------------------------------
__global__ __launch_bounds__(256) void out_ln(
    const float* __restrict__ A, const float* __restrict__ Wo,
    const float* __restrict__ bo, const float* __restrict__ x,
    const float* __restrict__ gamma, const float* __restrict__ beta,
    float* __restrict__ out)
{
    __shared__ float As[16][20];    // [k][row]
    __shared__ float Bs[16][260];   // [k][col]

    const int tid = threadIdx.x;
    const int row0 = blockIdx.x * 16;
    const int ty = tid >> 6;        // wave 0..3 -> rows ty*4..+3
    const int tx = tid & 63;        // cols tx*4..+3
    const int lrA = tid >> 4;       // 0..15 row
    const int lcA = tid & 15;       // k

    float acc[4][4] = {};

    for (int k0 = 0; k0 < 256; k0 += 16) {
        const float aval = A[(size_t)(row0 + lrA) * 256 + k0 + lcA];
        const float4 w0 = *(const float4*)(Wo + (size_t)tid * 256 + k0);
        const float4 w1 = *(const float4*)(Wo + (size_t)tid * 256 + k0 + 4);
        const float4 w2 = *(const float4*)(Wo + (size_t)tid * 256 + k0 + 8);
        const float4 w3 = *(const float4*)(Wo + (size_t)tid * 256 + k0 + 12);
        __syncthreads();
        As[lcA][lrA] = aval;
        Bs[ 0][tid] = w0.x; Bs[ 1][tid] = w0.y; Bs[ 2][tid] = w0.z; Bs[ 3][tid] = w0.w;
        Bs[ 4][tid] = w1.x; Bs[ 5][tid] = w1.y; Bs[ 6][tid] = w1.z; Bs[ 7][tid] = w1.w;
        Bs[ 8][tid] = w2.x; Bs[ 9][tid] = w2.y; Bs[10][tid] = w2.z; Bs[11][tid] = w2.w;
        Bs[12][tid] = w3.x; Bs[13][tid] = w3.y; Bs[14][tid] = w3.z; Bs[15][tid] = w3.w;
        __syncthreads();
#pragma unroll
        for (int kk = 0; kk < 16; kk++) {
            const float4 a4 = *(const float4*)&As[kk][ty * 4];
            const float4 b4 = *(const float4*)&Bs[kk][tx * 4];
            const float av[4] = {a4.x, a4.y, a4.z, a4.w};
            const float bw[4] = {b4.x, b4.y, b4.z, b4.w};
#pragma unroll
            for (int r = 0; r < 4; r++)
#pragma unroll
                for (int c2 = 0; c2 < 4; c2++)
                    acc[r][c2] = fmaf(av[r], bw[c2], acc[r][c2]);
        }
    }

    // epilogue: bias + residual, then LN per row (wave-wide reduce)
    const int gc = tx * 4;
    const float4 b4 = *(const float4*)(bo + gc);
    const float4 g4 = *(const float4*)(gamma + gc);
    const float4 be4 = *(const float4*)(beta + gc);
#pragma unroll
    for (int r = 0; r < 4; r++) {
        const int gr = row0 + ty * 4 + r;
        const float4 rv = *(const float4*)(x + (size_t)gr * 256 + gc);
        float h0 = acc[r][0] + b4.x + rv.x;
        float h1 = acc[r][1] + b4.y + rv.y;
        float h2 = acc[r][2] + b4.z + rv.z;
        float h3 = acc[r][3] + b4.w + rv.w;
        float s = (h0 + h1) + (h2 + h3);
#pragma unroll
        for (int o = 1; o < 64; o <<= 1) s += __shfl_xor(s, o);
        const float mu = s * (1.f / 256.f);
        const float d0 = h0 - mu, d1 = h1 - mu, d2 = h2 - mu, d3 = h3 - mu;
        float sq = (d0 * d0 + d1 * d1) + (d2 * d2 + d3 * d3);
#pragma unroll
        for (int o = 1; o < 64; o <<= 1) sq += __shfl_xor(sq, o);
        const float rstd = rsqrtf(sq * (1.f / 256.f) + 1e-5f);
        float4 o4;
        o4.x = d0 * rstd * g4.x + be4.x;
        o4.y = d1 * rstd * g4.y + be4.y;
        o4.z = d2 * rstd * g4.z + be4.z;
        o4.w = d3 * rstd * g4.w + be4.w;
        *(float4*)(out + (size_t)gr * 256 + gc) = o4;
    }
}

// ---------------------------------------------------------------------------
extern "C" void kernel_launch(void* const* d_in, const int* in_sizes, int n_in,
                              void* d_out, int out_size, void* d_ws, size_t ws_size,
                              hipStream_t stream)
{
    const float* x     = (const float*)d_in[0];
    const float* adj   = (const float*)d_in[1];
    const float* Wq    = (const float*)d_in[2];
    const float* bq    = (const float*)d_in[3];
    const float* Wk    = (const float*)d_in[4];
    const float* bk    = (const float*)d_in[5];
    const float* Wv    = (const float*)d_in[6];
    const float* bv    = (const float*)d_in[7];
    const float* Wo    = (const float*)d_in[8];
    const float* bo    = (const float*)d_in[9];
    const float* gamma = (const float*)d_in[10];
    const float* beta  = (const float*)d_in[11];

    float* ws = (float*)d_ws;
    const size_t NM = (size_t)NN * DIMV;   // 1M floats
    float* Qb = ws;
    float* Kb = ws + NM;
    float* Vb = ws + 2 * NM;
    float* AT = ws + 3 * NM;
    float* S  = ws + 4 * NM;   // 256 floats

    (void)hipMemsetAsync(S, 0, 256 * sizeof(float), stream);
    qkv_gemm<<<dim3(64, 2, 3), 256, 0, stream>>>(x, Wq, Wk, Wv, bq, bk, bv, Qb, Kb, Vb, S);
    attn_v3<<<NN, 512, 0, stream>>>(Qb, Kb, Vb, adj, S, AT);
    out_ln<<<256, 256, 0, stream>>>(AT, Wo, bo, x, gamma, beta, (float*)d_out);
}

// Round 8
// 248.093 us; speedup vs baseline: 1.3349x; 1.3349x over previous
//
#include <hip/hip_runtime.h>
#include <math.h>

#define NN 4096
#define ECAP 768   // max edges/row; Binomial(4096,0.05): mean 205, sd 14 (40 sigma)

typedef float f32x4 __attribute__((ext_vector_type(4)));

__device__ __forceinline__ float bf2f(unsigned short u) {
    union { unsigned int i; float f; } c; c.i = ((unsigned int)u) << 16; return c.f;
}
__device__ __forceinline__ unsigned short f2bf(float f) {
    union { float f; unsigned int i; } c; c.f = f;
    const unsigned int r = c.i + 0x7FFFu + ((c.i >> 16) & 1u);   // round-nearest-even
    return (unsigned short)(r >> 16);
}

// ---------------------------------------------------------------------------
// QKV GEMM (R1-measured shape): tile 64x64, BK=32, 256 thr, 4x4 microtile.
// grid (64 mb, 4 nb, 3 which). which==0 -> Q fp32; 1 -> K bf16; 2 -> V bf16
// + exact fp32 column sums into S (LDS-reduced, 64 atomics/block).
// ---------------------------------------------------------------------------
__global__ __launch_bounds__(256) void qkv_gemm(
    const float* __restrict__ x,
    const float* __restrict__ Wq, const float* __restrict__ Wk, const float* __restrict__ Wv,
    const float* __restrict__ bq, const float* __restrict__ bk, const float* __restrict__ bv,
    float* __restrict__ Q, unsigned short* __restrict__ Kb, unsigned short* __restrict__ Vb,
    float* __restrict__ S)
{
    __shared__ float As[32][68];
    __shared__ float Bs[32][68];

    const int which = blockIdx.z;
    const float* __restrict__ W    = which == 0 ? Wq : (which == 1 ? Wk : Wv);
    const float* __restrict__ bias = which == 0 ? bq : (which == 1 ? bk : bv);

    const int tid = threadIdx.x;
    const int tx = tid & 15, ty = tid >> 4;
    const int row0 = blockIdx.x * 64, col0 = blockIdx.y * 64;
    const int lr = tid >> 3;          // 0..31
    const int lc = (tid & 7) * 4;     // 0,4,...,28

    float acc[4][4] = {};

    for (int k0 = 0; k0 < 256; k0 += 32) {
        const float4 a0 = *(const float4*)(x + (size_t)(row0 + lr) * 256 + k0 + lc);
        const float4 a1 = *(const float4*)(x + (size_t)(row0 + lr + 32) * 256 + k0 + lc);
        const float4 w0 = *(const float4*)(W + (size_t)(col0 + lr) * 256 + k0 + lc);
        const float4 w1 = *(const float4*)(W + (size_t)(col0 + lr + 32) * 256 + k0 + lc);
        __syncthreads();
        As[lc + 0][lr] = a0.x; As[lc + 1][lr] = a0.y; As[lc + 2][lr] = a0.z; As[lc + 3][lr] = a0.w;
        As[lc + 0][lr + 32] = a1.x; As[lc + 1][lr + 32] = a1.y; As[lc + 2][lr + 32] = a1.z; As[lc + 3][lr + 32] = a1.w;
        Bs[lc + 0][lr] = w0.x; Bs[lc + 1][lr] = w0.y; Bs[lc + 2][lr] = w0.z; Bs[lc + 3][lr] = w0.w;
        Bs[lc + 0][lr + 32] = w1.x; Bs[lc + 1][lr + 32] = w1.y; Bs[lc + 2][lr + 32] = w1.z; Bs[lc + 3][lr + 32] = w1.w;
        __syncthreads();
#pragma unroll
        for (int kk = 0; kk < 32; kk++) {
            const float4 av = *(const float4*)&As[kk][ty * 4];
            const float4 bv4 = *(const float4*)&Bs[kk][tx * 4];
            acc[0][0] = fmaf(av.x, bv4.x, acc[0][0]); acc[0][1] = fmaf(av.x, bv4.y, acc[0][1]);
            acc[0][2] = fmaf(av.x, bv4.z, acc[0][2]); acc[0][3] = fmaf(av.x, bv4.w, acc[0][3]);
            acc[1][0] = fmaf(av.y, bv4.x, acc[1][0]); acc[1][1] = fmaf(av.y, bv4.y, acc[1][1]);
            acc[1][2] = fmaf(av.y, bv4.z, acc[1][2]); acc[1][3] = fmaf(av.y, bv4.w, acc[1][3]);
            acc[2][0] = fmaf(av.z, bv4.x, acc[2][0]); acc[2][1] = fmaf(av.z, bv4.y, acc[2][1]);
            acc[2][2] = fmaf(av.z, bv4.z, acc[2][2]); acc[2][3] = fmaf(av.z, bv4.w, acc[2][3]);
            acc[3][0] = fmaf(av.w, bv4.x, acc[3][0]); acc[3][1] = fmaf(av.w, bv4.y, acc[3][1]);
            acc[3][2] = fmaf(av.w, bv4.z, acc[3][2]); acc[3][3] = fmaf(av.w, bv4.w, acc[3][3]);
        }
    }

    const int gc = col0 + tx * 4;
    const float4 b4 = *(const float4*)(bias + gc);
    float cs0 = 0.f, cs1 = 0.f, cs2 = 0.f, cs3 = 0.f;
#pragma unroll
    for (int r = 0; r < 4; r++) {
        const int gr = row0 + ty * 4 + r;
        float4 v;
        v.x = acc[r][0] + b4.x; v.y = acc[r][1] + b4.y;
        v.z = acc[r][2] + b4.z; v.w = acc[r][3] + b4.w;
        if (which == 0) {
            *(float4*)(Q + (size_t)gr * 256 + gc) = v;
        } else {
            ushort4 pk;
            pk.x = f2bf(v.x); pk.y = f2bf(v.y); pk.z = f2bf(v.z); pk.w = f2bf(v.w);
            *(ushort4*)((which == 1 ? Kb : Vb) + (size_t)gr * 256 + gc) = pk;
            cs0 += v.x; cs1 += v.y; cs2 += v.z; cs3 += v.w;
        }
    }
    if (which == 2) {   // exact fp32 column sums of V
        __syncthreads();
        float* red = &As[0][0];
        red[ty * 68 + tx * 4 + 0] = cs0;
        red[ty * 68 + tx * 4 + 1] = cs1;
        red[ty * 68 + tx * 4 + 2] = cs2;
        red[ty * 68 + tx * 4 + 3] = cs3;
        __syncthreads();
        if (ty == 0) {
#pragma unroll
            for (int c = 0; c < 4; c++) {
                float s = 0.f;
#pragma unroll
                for (int t = 0; t < 16; t++) s += red[t * 68 + tx * 4 + c];
                atomicAdd(&S[gc + c], s);
            }
        }
    }
}

// ---------------------------------------------------------------------------
// Fused sparse attention, two-phase, bf16 K/V (fits 4MB/XCD L2).
// One block (512 thr, 8 waves) per row i.
//  A: nontemporal adj scan, deterministic cross-wave scan compaction -> lj[]
//  B: QK: wave-per-edge 4-edge ILP, 512B bf16 K-row coalesced (ushort4/lane),
//     fp32 dot + 16-lane shfl reduce; w = exp2f(s*log2e)-1 (scale folded in q)
//  C: PV: 2 dim-groups x 256 dims, 8-way unrolled bf16 V loads
//  D: out = (num + S) / (den + 4096)
// ---------------------------------------------------------------------------
__global__ __launch_bounds__(512, 4) void attn_v4(
    const float* __restrict__ Q, const unsigned short* __restrict__ K,
    const unsigned short* __restrict__ V, const float* __restrict__ adj,
    const float* __restrict__ S, float* __restrict__ out)
{
    __shared__ unsigned short lj[ECAP];
    __shared__ float wgt[ECAP * 4];
    __shared__ float pnum[2][256];
    __shared__ float pden[2][4];
    __shared__ int wtot[8], wbase[8], cnt;

    const int i = blockIdx.x;
    const int tid = threadIdx.x;
    const int wave = tid >> 6;
    const int lane = tid & 63;

    // ---- stage A: compact adjacency row (8 cols/thread, nontemporal) ----
    const f32x4* __restrict__ arow = (const f32x4*)(adj + (size_t)i * NN);
    const f32x4 a0 = __builtin_nontemporal_load(arow + 2 * tid);
    const f32x4 a1 = __builtin_nontemporal_load(arow + 2 * tid + 1);
    const int c = (a0.x != 0.f) + (a0.y != 0.f) + (a0.z != 0.f) + (a0.w != 0.f)
                + (a1.x != 0.f) + (a1.y != 0.f) + (a1.z != 0.f) + (a1.w != 0.f);
    int incl = c;
#pragma unroll
    for (int s = 1; s < 64; s <<= 1) {
        const int v = __shfl_up(incl, s);
        if (lane >= s) incl += v;
    }
    if (lane == 63) wtot[wave] = incl;
    __syncthreads();
    if (tid == 0) {
        int s = 0;
#pragma unroll
        for (int w = 0; w < 8; w++) { wbase[w] = s; s += wtot[w]; }
        cnt = s;
    }
    __syncthreads();
    {
        int p = wbase[wave] + incl - c;
        const int j0 = tid * 8;
        if (a0.x != 0.f && p < ECAP) lj[p++] = (unsigned short)(j0 + 0);
        if (a0.y != 0.f && p < ECAP) lj[p++] = (unsigned short)(j0 + 1);
        if (a0.z != 0.f && p < ECAP) lj[p++] = (unsigned short)(j0 + 2);
        if (a0.w != 0.f && p < ECAP) lj[p++] = (unsigned short)(j0 + 3);
        if (a1.x != 0.f && p < ECAP) lj[p++] = (unsigned short)(j0 + 4);
        if (a1.y != 0.f && p < ECAP) lj[p++] = (unsigned short)(j0 + 5);
        if (a1.z != 0.f && p < ECAP) lj[p++] = (unsigned short)(j0 + 6);
        if (a1.w != 0.f && p < ECAP) lj[p++] = (unsigned short)(j0 + 7);
    }
    __syncthreads();
    const int m = min(cnt, ECAP);

    // ---- stage B: QK scores ----
    const float4 qraw = ((const float4*)(Q + (size_t)i * 256))[lane];
    const float QS = 0.125f * 1.44269504089f;   // fold 1/sqrt(dk) and log2(e)
    const float4 qv = {qraw.x * QS, qraw.y * QS, qraw.z * QS, qraw.w * QS};
    for (int e0 = wave * 4; e0 < m; e0 += 32) {
        int jj[4];
#pragma unroll
        for (int u = 0; u < 4; u++)
            jj[u] = (e0 + u < m) ? (int)lj[e0 + u] : (int)lj[e0];
        ushort4 kv[4];
#pragma unroll
        for (int u = 0; u < 4; u++)
            kv[u] = ((const ushort4*)(K + (size_t)jj[u] * 256))[lane];
#pragma unroll
        for (int u = 0; u < 4; u++) {
            float d = bf2f(kv[u].x) * qv.x + bf2f(kv[u].y) * qv.y
                    + bf2f(kv[u].z) * qv.z + bf2f(kv[u].w) * qv.w;
            d += __shfl_xor(d, 1);
            d += __shfl_xor(d, 2);
            d += __shfl_xor(d, 4);
            d += __shfl_xor(d, 8);
            if ((lane & 15) == 0 && e0 + u < m)
                wgt[(e0 + u) * 4 + (lane >> 4)] = exp2f(d) - 1.f;
        }
    }
    __syncthreads();

    // ---- stage C: PV ----
    const int g = tid >> 8;        // 0 or 1
    const int d = tid & 255;
    const int head = d >> 6;
    float num = 0.f, den = 0.f;
    int e = g;
    for (; e + 14 < m; e += 16) {
        float w[8];
#pragma unroll
        for (int u = 0; u < 8; u++) w[u] = wgt[(e + 2 * u) * 4 + head];
        float v[8];
#pragma unroll
        for (int u = 0; u < 8; u++)
            v[u] = bf2f(V[(size_t)lj[e + 2 * u] * 256 + d]);
#pragma unroll
        for (int u = 0; u < 8; u++) { num = fmaf(w[u], v[u], num); den += w[u]; }
    }
    for (; e < m; e += 2) {
        const float w = wgt[e * 4 + head];
        num = fmaf(w, bf2f(V[(size_t)lj[e] * 256 + d]), num);
        den += w;
    }
    pnum[g][d] = num;
    if ((d & 63) == 0) pden[g][head] = den;
    __syncthreads();

    // ---- stage D: output ----
    if (tid < 256) {
        const int h = tid >> 6;
        const float dn = pden[0][h] + pden[1][h] + 4096.0f;
        out[(size_t)i * 256 + tid] = (pnum[0][tid] + pnum[1][tid] + S[tid]) / dn;
    }
}

// ---------------------------------------------------------------------------
// Out-projection GEMM (R1 shape): tile 64x64, 4x4 micro, + bias + residual.
// ---------------------------------------------------------------------------
__global__ __launch_bounds__(256) void out_gemm(
    const float* __restrict__ A, const float* __restrict__ Wo,
    const float* __restrict__ bo, const float* __restrict__ x,
    float* __restrict__ H)
{
    __shared__ float As[32][68];
    __shared__ float Bs[32][68];
    const int tid = threadIdx.x;
    const int tx = tid & 15, ty = tid >> 4;
    const int row0 = blockIdx.x * 64, col0 = blockIdx.y * 64;
    const int lr = tid >> 3;
    const int lc = (tid & 7) * 4;

    float acc[4][4] = {};

    for (int k0 = 0; k0 < 256; k0 += 32) {
        const float4 a0 = *(const float4*)(A + (size_t)(row0 + lr) * 256 + k0 + lc);
        const float4 a1 = *(const float4*)(A + (size_t)(row0 + lr + 32) * 256 + k0 + lc);
        const float4 w0 = *(const float4*)(Wo + (size_t)(col0 + lr) * 256 + k0 + lc);
        const float4 w1 = *(const float4*)(Wo + (size_t)(col0 + lr + 32) * 256 + k0 + lc);
        __syncthreads();
        As[lc + 0][lr] = a0.x; As[lc + 1][lr] = a0.y; As[lc + 2][lr] = a0.z; As[lc + 3][lr] = a0.w;
        As[lc + 0][lr + 32] = a1.x; As[lc + 1][lr + 32] = a1.y; As[lc + 2][lr + 32] = a1.z; As[lc + 3][lr + 32] = a1.w;
        Bs[lc + 0][lr] = w0.x; Bs[lc + 1][lr] = w0.y; Bs[lc + 2][lr] = w0.z; Bs[lc + 3][lr] = w0.w;
        Bs[lc + 0][lr + 32] = w1.x; Bs[lc + 1][lr + 32] = w1.y; Bs[lc + 2][lr + 32] = w1.z; Bs[lc + 3][lr + 32] = w1.w;
        __syncthreads();
#pragma unroll
        for (int kk = 0; kk < 32; kk++) {
            const float4 av = *(const float4*)&As[kk][ty * 4];
            const float4 bv4 = *(const float4*)&Bs[kk][tx * 4];
            acc[0][0] = fmaf(av.x, bv4.x, acc[0][0]); acc[0][1] = fmaf(av.x, bv4.y, acc[0][1]);
            acc[0][2] = fmaf(av.x, bv4.z, acc[0][2]); acc[0][3] = fmaf(av.x, bv4.w, acc[0][3]);
            acc[1][0] = fmaf(av.y, bv4.x, acc[1][0]); acc[1][1] = fmaf(av.y, bv4.y, acc[1][1]);
            acc[1][2] = fmaf(av.y, bv4.z, acc[1][2]); acc[1][3] = fmaf(av.y, bv4.w, acc[1][3]);
            acc[2][0] = fmaf(av.z, bv4.x, acc[2][0]); acc[2][1] = fmaf(av.z, bv4.y, acc[2][1]);
            acc[2][2] = fmaf(av.z, bv4.z, acc[2][2]); acc[2][3] = fmaf(av.z, bv4.w, acc[2][3]);
            acc[3][0] = fmaf(av.w, bv4.x, acc[3][0]); acc[3][1] = fmaf(av.w, bv4.y, acc[3][1]);
            acc[3][2] = fmaf(av.w, bv4.z, acc[3][2]); acc[3][3] = fmaf(av.w, bv4.w, acc[3][3]);
        }
    }
#pragma unroll
    for (int r = 0; r < 4; r++) {
        const int gr = row0 + ty * 4 + r;
        const int gc = col0 + tx * 4;
        const float4 rv = *(const float4*)(x + (size_t)gr * 256 + gc);
        float4 v;
        v.x = acc[r][0] + bo[gc + 0] + rv.x;
        v.y = acc[r][1] + bo[gc + 1] + rv.y;
        v.z = acc[r][2] + bo[gc + 2] + rv.z;
        v.w = acc[r][3] + bo[gc + 3] + rv.w;
        *(float4*)(H + (size_t)gr * 256 + gc) = v;
    }
}

// ---------------------------------------------------------------------------
// Row LayerNorm: 4 rows per block (wave per row).
// ---------------------------------------------------------------------------
__global__ __launch_bounds__(256) void ln_kernel(
    const float* __restrict__ H, const float* __restrict__ gamma,
    const float* __restrict__ beta, float* __restrict__ out)
{
    const int row = blockIdx.x * 4 + (threadIdx.x >> 6);
    const int lane = threadIdx.x & 63;
    const float4 v = ((const float4*)(H + (size_t)row * 256))[lane];
    float s = (v.x + v.y) + (v.z + v.w);
#pragma unroll
    for (int o = 1; o < 64; o <<= 1) s += __shfl_xor(s, o);
    const float mu = s * (1.f / 256.f);
    const float dx = v.x - mu, dy = v.y - mu, dz = v.z - mu, dw = v.w - mu;
    float sq = (dx * dx + dy * dy) + (dz * dz + dw * dw);
#pragma unroll
    for (int o = 1; o < 64; o <<= 1) sq += __shfl_xor(sq, o);
    const float rstd = rsqrtf(sq * (1.f / 256.f) + 1e-5f);
    const float4 g = ((const float4*)gamma)[lane];
    const float4 b = ((const float4*)beta)[lane];
    float4 o4;
    o4.x = dx * rstd * g.x + b.x;
    o4.y = dy * rstd * g.y + b.y;
    o4.z = dz * rstd * g.z + b.z;
    o4.w = dw * rstd * g.w + b.w;
    ((float4*)(out + (size_t)row * 256))[lane] = o4;
}

// ---------------------------------------------------------------------------
extern "C" void kernel_launch(void* const* d_in, const int* in_sizes, int n_in,
                              void* d_out, int out_size, void* d_ws, size_t ws_size,
                              hipStream_t stream)
{
    const float* x     = (const float*)d_in[0];
    const float* adj   = (const float*)d_in[1];
    const float* Wq    = (const float*)d_in[2];
    const float* bq    = (const float*)d_in[3];
    const float* Wk    = (const float*)d_in[4];
    const float* bk    = (const float*)d_in[5];
    const float* Wv    = (const float*)d_in[6];
    const float* bv    = (const float*)d_in[7];
    const float* Wo    = (const float*)d_in[8];
    const float* bo    = (const float*)d_in[9];
    const float* gamma = (const float*)d_in[10];
    const float* beta  = (const float*)d_in[11];

    float* ws = (float*)d_ws;
    const size_t NM = (size_t)NN * 256;          // 1M elements
    float* Qb          = ws;                      // fp32 [NM]
    unsigned short* Kb = (unsigned short*)(ws + NM);        // bf16 [NM]
    unsigned short* Vb = Kb + NM;                 // bf16 [NM]
    float* AT          = ws + 2 * NM;             // fp32 [NM] (after Kb+Vb = NM floats)
    float* H           = ws + 3 * NM;             // fp32 [NM]
    float* S           = ws + 4 * NM;             // fp32 [256]

    (void)hipMemsetAsync(S, 0, 256 * sizeof(float), stream);
    qkv_gemm<<<dim3(64, 4, 3), 256, 0, stream>>>(x, Wq, Wk, Wv, bq, bk, bv, Qb, Kb, Vb, S);
    attn_v4<<<NN, 512, 0, stream>>>(Qb, Kb, Vb, adj, S, AT);
    out_gemm<<<dim3(64, 4), 256, 0, stream>>>(AT, Wo, bo, x, H);
    ln_kernel<<<1024, 256, 0, stream>>>(H, gamma, beta, (float*)d_out);
}

// Round 15
// 238.542 us; speedup vs baseline: 1.3884x; 1.0400x over previous
//
#include <hip/hip_runtime.h>
#include <math.h>

#define NN 4096
#define ECAP 768   // max edges/row; Binomial(4096,0.05): mean 205, sd 14 (40 sigma)

typedef float f32x4 __attribute__((ext_vector_type(4)));

__device__ __forceinline__ float bf2f(unsigned short u) {
    union { unsigned int i; float f; } c; c.i = ((unsigned int)u) << 16; return c.f;
}
__device__ __forceinline__ unsigned short f2bf(float f) {
    union { float f; unsigned int i; } c; c.f = f;
    const unsigned int r = c.i + 0x7FFFu + ((c.i >> 16) & 1u);   // round-nearest-even
    return (unsigned short)(r >> 16);
}

// ---------------------------------------------------------------------------
// QKV GEMM: tile 128x128, BK=32, 256 thr, 8x8 microtile (1 B/FLOP LDS).
// grid (32 mb, 2 nb, 3 which). which==0 -> Q fp32; 1 -> K bf16; 2 -> V bf16
// + exact fp32 column sums of V into S (LDS-reduced, 128 atomics/block).
// B-column store XOR-swizzled to break the 4-way read bank conflict.
// ---------------------------------------------------------------------------
__device__ __forceinline__ int bswz(int col) {           // bijective col swizzle
    return col ^ (((col >> 5) & 3) << 2);
}

__global__ __launch_bounds__(256) void qkv_gemm(
    const float* __restrict__ x,
    const float* __restrict__ Wq, const float* __restrict__ Wk, const float* __restrict__ Wv,
    const float* __restrict__ bq, const float* __restrict__ bk, const float* __restrict__ bv,
    float* __restrict__ Q, unsigned short* __restrict__ Kb, unsigned short* __restrict__ Vb,
    float* __restrict__ S)
{
    __shared__ float As[32][132];
    __shared__ float Bs[32][132];

    const int which = blockIdx.z;
    const float* __restrict__ W    = which == 0 ? Wq : (which == 1 ? Wk : Wv);
    const float* __restrict__ bias = which == 0 ? bq : (which == 1 ? bk : bv);

    const int tid = threadIdx.x;
    const int row0 = blockIdx.x * 128, col0 = blockIdx.y * 128;
    const int lr = tid >> 1;              // 0..127 (row of A-tile / col of B-tile)
    const int lk = (tid & 1) * 16;        // k offset 0 / 16
    const int ty = tid >> 4, tx = tid & 15;
    const int lrs = bswz(lr);             // swizzled B store col

    float acc[8][8] = {};

    for (int k0 = 0; k0 < 256; k0 += 32) {
        float4 a[4], b[4];
#pragma unroll
        for (int j = 0; j < 4; j++) {
            a[j] = *(const float4*)(x + (size_t)(row0 + lr) * 256 + k0 + lk + 4 * j);
            b[j] = *(const float4*)(W + (size_t)(col0 + lr) * 256 + k0 + lk + 4 * j);
        }
        __syncthreads();
#pragma unroll
        for (int j = 0; j < 4; j++) {
            As[lk + 4 * j + 0][lr] = a[j].x; As[lk + 4 * j + 1][lr] = a[j].y;
            As[lk + 4 * j + 2][lr] = a[j].z; As[lk + 4 * j + 3][lr] = a[j].w;
            Bs[lk + 4 * j + 0][lrs] = b[j].x; Bs[lk + 4 * j + 1][lrs] = b[j].y;
            Bs[lk + 4 * j + 2][lrs] = b[j].z; Bs[lk + 4 * j + 3][lrs] = b[j].w;
        }
        __syncthreads();
#pragma unroll
        for (int kk = 0; kk < 32; kk++) {
            const float4 a0 = *(const float4*)&As[kk][ty * 8];
            const float4 a1 = *(const float4*)&As[kk][ty * 8 + 4];
            // cols tx*8..+3 sit contiguously at bswz(tx*8); cols +4..+7 at ^4
            // (XOR constant depends only on bits 5..6, equal for both halves)
            const int bc = bswz(tx * 8);
            const float4 b0 = *(const float4*)&Bs[kk][bc];
            const float4 b1 = *(const float4*)&Bs[kk][bc ^ 4];
            const float av[8] = {a0.x, a0.y, a0.z, a0.w, a1.x, a1.y, a1.z, a1.w};
            const float bw[8] = {b0.x, b0.y, b0.z, b0.w, b1.x, b1.y, b1.z, b1.w};
#pragma unroll
            for (int r = 0; r < 8; r++)
#pragma unroll
                for (int c = 0; c < 8; c++)
                    acc[r][c] = fmaf(av[r], bw[c], acc[r][c]);
        }
    }

    const int gc = col0 + tx * 8;
    const float4 blo = *(const float4*)(bias + gc);
    const float4 bhi = *(const float4*)(bias + gc + 4);
    float cs[8] = {};
#pragma unroll
    for (int r = 0; r < 8; r++) {
        const int gr = row0 + ty * 8 + r;
        float v[8];
        v[0] = acc[r][0] + blo.x; v[1] = acc[r][1] + blo.y;
        v[2] = acc[r][2] + blo.z; v[3] = acc[r][3] + blo.w;
        v[4] = acc[r][4] + bhi.x; v[5] = acc[r][5] + bhi.y;
        v[6] = acc[r][6] + bhi.z; v[7] = acc[r][7] + bhi.w;
        if (which == 0) {
            float4 o0, o1;
            o0.x = v[0]; o0.y = v[1]; o0.z = v[2]; o0.w = v[3];
            o1.x = v[4]; o1.y = v[5]; o1.z = v[6]; o1.w = v[7];
            *(float4*)(Q + (size_t)gr * 256 + gc) = o0;
            *(float4*)(Q + (size_t)gr * 256 + gc + 4) = o1;
        } else {
            ushort4 p0, p1;
            p0.x = f2bf(v[0]); p0.y = f2bf(v[1]); p0.z = f2bf(v[2]); p0.w = f2bf(v[3]);
            p1.x = f2bf(v[4]); p1.y = f2bf(v[5]); p1.z = f2bf(v[6]); p1.w = f2bf(v[7]);
            unsigned short* C = (which == 1 ? Kb : Vb);
            *(ushort4*)(C + (size_t)gr * 256 + gc) = p0;
            *(ushort4*)(C + (size_t)gr * 256 + gc + 4) = p1;
#pragma unroll
            for (int c = 0; c < 8; c++) cs[c] += v[c];
        }
    }
    if (which == 2) {   // exact fp32 column sums of V
        __syncthreads();
        float* red = &As[0][0];          // reuse; 128 cols x stride 17 = 2176 floats
#pragma unroll
        for (int c = 0; c < 8; c++) red[(tx * 8 + c) * 17 + ty] = cs[c];
        __syncthreads();
        if (tid < 128) {
            float s = 0.f;
#pragma unroll
            for (int t = 0; t < 16; t++) s += red[tid * 17 + t];
            atomicAdd(&S[col0 + tid], s);
        }
    }
}

// ---------------------------------------------------------------------------
// Sparse attention v5: VALU-lean. One block (512 thr, 8 waves) per row i.
//  A: nontemporal adj scan -> lj[] (j-sorted); pad to mp = ceil32(m), lj[pad]=0
//  B: wave-per-edge 4-ILP; 32-bit offsets; w=exp2(d)-1 (pads get w=0) -> wgt
//  C: 4 groups x 128 thr; group g takes e%4==g; ushort2 V loads, 8-deep ILP.
//     NOTE: every thread in a head-group accumulates the SAME full den
//     (it iterates all of its group's edges) -> one lane writes it, NO reduce.
//  D: out = (num + S) / (den + 4096)
// ---------------------------------------------------------------------------
__global__ __launch_bounds__(512, 4) void attn_v5(
    const float* __restrict__ Q, const unsigned short* __restrict__ K,
    const unsigned short* __restrict__ V, const float* __restrict__ adj,
    const float* __restrict__ S, float* __restrict__ out)
{
    __shared__ unsigned short lj[ECAP];
    __shared__ float wgt[ECAP * 4];
    __shared__ float pnum[4][256];
    __shared__ float pden[4][4];
    __shared__ int wtot[8], wbase[8], cnt;

    const int i = blockIdx.x;
    const int tid = threadIdx.x;
    const int wave = tid >> 6;
    const int lane = tid & 63;

    // ---- stage A: compact adjacency row ----
    const f32x4* __restrict__ arow = (const f32x4*)(adj + (size_t)i * NN);
    const f32x4 a0 = __builtin_nontemporal_load(arow + 2 * tid);
    const f32x4 a1 = __builtin_nontemporal_load(arow + 2 * tid + 1);
    const int c = (a0.x != 0.f) + (a0.y != 0.f) + (a0.z != 0.f) + (a0.w != 0.f)
                + (a1.x != 0.f) + (a1.y != 0.f) + (a1.z != 0.f) + (a1.w != 0.f);
    int incl = c;
#pragma unroll
    for (int s = 1; s < 64; s <<= 1) {
        const int v = __shfl_up(incl, s);
        if (lane >= s) incl += v;
    }
    if (lane == 63) wtot[wave] = incl;
    __syncthreads();
    if (tid == 0) {
        int s = 0;
#pragma unroll
        for (int w = 0; w < 8; w++) { wbase[w] = s; s += wtot[w]; }
        cnt = s;
    }
    __syncthreads();
    {
        int p = wbase[wave] + incl - c;
        const int j0 = tid * 8;
        if (a0.x != 0.f && p < ECAP) lj[p++] = (unsigned short)(j0 + 0);
        if (a0.y != 0.f && p < ECAP) lj[p++] = (unsigned short)(j0 + 1);
        if (a0.z != 0.f && p < ECAP) lj[p++] = (unsigned short)(j0 + 2);
        if (a0.w != 0.f && p < ECAP) lj[p++] = (unsigned short)(j0 + 3);
        if (a1.x != 0.f && p < ECAP) lj[p++] = (unsigned short)(j0 + 4);
        if (a1.y != 0.f && p < ECAP) lj[p++] = (unsigned short)(j0 + 5);
        if (a1.z != 0.f && p < ECAP) lj[p++] = (unsigned short)(j0 + 6);
        if (a1.w != 0.f && p < ECAP) lj[p++] = (unsigned short)(j0 + 7);
    }
    __syncthreads();
    const int m = min(cnt, ECAP);
    const int mp = min((m + 31) & ~31, ECAP);
    for (int e = m + tid; e < mp; e += 512) lj[e] = 0;   // pad: valid row, w forced 0
    __syncthreads();

    // ---- stage B: QK scores (32-bit addressing, padded loop) ----
    const float4 qraw = ((const float4*)(Q + (size_t)i * 256))[lane];
    const float QS = 0.125f * 1.44269504089f;   // fold 1/sqrt(dk) and log2(e)
    const float4 qv = {qraw.x * QS, qraw.y * QS, qraw.z * QS, qraw.w * QS};
    const unsigned lane4 = (unsigned)(lane << 2);
    for (int e0 = wave * 4; e0 < mp; e0 += 32) {
        unsigned off[4];
#pragma unroll
        for (int u = 0; u < 4; u++)
            off[u] = ((unsigned)lj[e0 + u] << 8) + lane4;
        ushort4 kv[4];
#pragma unroll
        for (int u = 0; u < 4; u++)
            kv[u] = *(const ushort4*)(K + off[u]);
#pragma unroll
        for (int u = 0; u < 4; u++) {
            float d = bf2f(kv[u].x) * qv.x + bf2f(kv[u].y) * qv.y
                    + bf2f(kv[u].z) * qv.z + bf2f(kv[u].w) * qv.w;
            d += __shfl_xor(d, 1);
            d += __shfl_xor(d, 2);
            d += __shfl_xor(d, 4);
            d += __shfl_xor(d, 8);
            float w = exp2f(d) - 1.f;
            if (e0 + u >= m) w = 0.f;
            if ((lane & 15) == 0) wgt[(e0 + u) * 4 + (lane >> 4)] = w;
        }
    }
    __syncthreads();

    // ---- stage C: PV (4 groups x 128 thr, ushort2 loads, 8-deep ILP) ----
    const int g = tid >> 7;         // 0..3
    const int t = tid & 127;
    const int d0 = t * 2;
    const int head = t >> 5;
    float nx = 0.f, ny = 0.f, den = 0.f;
    for (int e = g; e < mp; e += 32) {
#pragma unroll
        for (int u = 0; u < 8; u++) {
            const int ee = e + 4 * u;
            const float w = wgt[ee * 4 + head];
            const unsigned off = ((unsigned)lj[ee] << 8) + (unsigned)d0;
            const ushort2 v2 = *(const ushort2*)(V + off);
            nx = fmaf(w, bf2f(v2.x), nx);
            ny = fmaf(w, bf2f(v2.y), ny);
            den += w;
        }
    }
    pnum[g][d0] = nx;
    pnum[g][d0 + 1] = ny;
    if ((t & 31) == 0) pden[g][head] = den;   // full sum already; no reduce
    __syncthreads();

    // ---- stage D: output ----
    if (tid < 256) {
        const int h = tid >> 6;
        const float dn = (pden[0][h] + pden[1][h]) + (pden[2][h] + pden[3][h]) + 4096.0f;
        const float nm = (pnum[0][tid] + pnum[1][tid]) + (pnum[2][tid] + pnum[3][tid]) + S[tid];
        out[(size_t)i * 256 + tid] = nm / dn;
    }
}

// ---------------------------------------------------------------------------
// Out-projection GEMM (unchanged from R8): tile 64x64, 4x4 micro, +bias+resid.
// ---------------------------------------------------------------------------
__global__ __launch_bounds__(256) void out_gemm(
    const float* __restrict__ A, const float* __restrict__ Wo,
    const float* __restrict__ bo, const float* __restrict__ x,
    float* __restrict__ H)
{
    __shared__ float As[32][68];
    __shared__ float Bs[32][68];
    const int tid = threadIdx.x;
    const int tx = tid & 15, ty = tid >> 4;
    const int row0 = blockIdx.x * 64, col0 = blockIdx.y * 64;
    const int lr = tid >> 3;
    const int lc = (tid & 7) * 4;

    float acc[4][4] = {};

    for (int k0 = 0; k0 < 256; k0 += 32) {
        const float4 a0 = *(const float4*)(A + (size_t)(row0 + lr) * 256 + k0 + lc);
        const float4 a1 = *(const float4*)(A + (size_t)(row0 + lr + 32) * 256 + k0 + lc);
        const float4 w0 = *(const float4*)(Wo + (size_t)(col0 + lr) * 256 + k0 + lc);
        const float4 w1 = *(const float4*)(Wo + (size_t)(col0 + lr + 32) * 256 + k0 + lc);
        __syncthreads();
        As[lc + 0][lr] = a0.x; As[lc + 1][lr] = a0.y; As[lc + 2][lr] = a0.z; As[lc + 3][lr] = a0.w;
        As[lc + 0][lr + 32] = a1.x; As[lc + 1][lr + 32] = a1.y; As[lc + 2][lr + 32] = a1.z; As[lc + 3][lr + 32] = a1.w;
        Bs[lc + 0][lr] = w0.x; Bs[lc + 1][lr] = w0.y; Bs[lc + 2][lr] = w0.z; Bs[lc + 3][lr] = w0.w;
        Bs[lc + 0][lr + 32] = w1.x; Bs[lc + 1][lr + 32] = w1.y; Bs[lc + 2][lr + 32] = w1.z; Bs[lc + 3][lr + 32] = w1.w;
        __syncthreads();
#pragma unroll
        for (int kk = 0; kk < 32; kk++) {
            const float4 av = *(const float4*)&As[kk][ty * 4];
            const float4 bv4 = *(const float4*)&Bs[kk][tx * 4];
            acc[0][0] = fmaf(av.x, bv4.x, acc[0][0]); acc[0][1] = fmaf(av.x, bv4.y, acc[0][1]);
            acc[0][2] = fmaf(av.x, bv4.z, acc[0][2]); acc[0][3] = fmaf(av.x, bv4.w, acc[0][3]);
            acc[1][0] = fmaf(av.y, bv4.x, acc[1][0]); acc[1][1] = fmaf(av.y, bv4.y, acc[1][1]);
            acc[1][2] = fmaf(av.y, bv4.z, acc[1][2]); acc[1][3] = fmaf(av.y, bv4.w, acc[1][3]);
            acc[2][0] = fmaf(av.z, bv4.x, acc[2][0]); acc[2][1] = fmaf(av.z, bv4.y, acc[2][1]);
            acc[2][2] = fmaf(av.z, bv4.z, acc[2][2]); acc[2][3] = fmaf(av.z, bv4.w, acc[2][3]);
            acc[3][0] = fmaf(av.w, bv4.x, acc[3][0]); acc[3][1] = fmaf(av.w, bv4.y, acc[3][1]);
            acc[3][2] = fmaf(av.w, bv4.z, acc[3][2]); acc[3][3] = fmaf(av.w, bv4.w, acc[3][3]);
        }
    }
#pragma unroll
    for (int r = 0; r < 4; r++) {
        const int gr = row0 + ty * 4 + r;
        const int gc = col0 + tx * 4;
        const float4 rv = *(const float4*)(x + (size_t)gr * 256 + gc);
        float4 v;
        v.x = acc[r][0] + bo[gc + 0] + rv.x;
        v.y = acc[r][1] + bo[gc + 1] + rv.y;
        v.z = acc[r][2] + bo[gc + 2] + rv.z;
        v.w = acc[r][3] + bo[gc + 3] + rv.w;
        *(float4*)(H + (size_t)gr * 256 + gc) = v;
    }
}

// ---------------------------------------------------------------------------
// Row LayerNorm (unchanged from R8).
// ---------------------------------------------------------------------------
__global__ __launch_bounds__(256) void ln_kernel(
    const float* __restrict__ H, const float* __restrict__ gamma,
    const float* __restrict__ beta, float* __restrict__ out)
{
    const int row = blockIdx.x * 4 + (threadIdx.x >> 6);
    const int lane = threadIdx.x & 63;
    const float4 v = ((const float4*)(H + (size_t)row * 256))[lane];
    float s = (v.x + v.y) + (v.z + v.w);
#pragma unroll
    for (int o = 1; o < 64; o <<= 1) s += __shfl_xor(s, o);
    const float mu = s * (1.f / 256.f);
    const float dx = v.x - mu, dy = v.y - mu, dz = v.z - mu, dw = v.w - mu;
    float sq = (dx * dx + dy * dy) + (dz * dz + dw * dw);
#pragma unroll
    for (int o = 1; o < 64; o <<= 1) sq += __shfl_xor(sq, o);
    const float rstd = rsqrtf(sq * (1.f / 256.f) + 1e-5f);
    const float4 g = ((const float4*)gamma)[lane];
    const float4 b = ((const float4*)beta)[lane];
    float4 o4;
    o4.x = dx * rstd * g.x + b.x;
    o4.y = dy * rstd * g.y + b.y;
    o4.z = dz * rstd * g.z + b.z;
    o4.w = dw * rstd * g.w + b.w;
    ((float4*)(out + (size_t)row * 256))[lane] = o4;
}

// ---------------------------------------------------------------------------
extern "C" void kernel_launch(void* const* d_in, const int* in_sizes, int n_in,
                              void* d_out, int out_size, void* d_ws, size_t ws_size,
                              hipStream_t stream)
{
    const float* x     = (const float*)d_in[0];
    const float* adj   = (const float*)d_in[1];
    const float* Wq    = (const float*)d_in[2];
    const float* bq    = (const float*)d_in[3];
    const float* Wk    = (const float*)d_in[4];
    const float* bk    = (const float*)d_in[5];
    const float* Wv    = (const float*)d_in[6];
    const float* bv    = (const float*)d_in[7];
    const float* Wo    = (const float*)d_in[8];
    const float* bo    = (const float*)d_in[9];
    const float* gamma = (const float*)d_in[10];
    const float* beta  = (const float*)d_in[11];

    float* ws = (float*)d_ws;
    const size_t NM = (size_t)NN * 256;           // 1M elements
    float* Qb          = ws;                      // fp32 [NM]
    unsigned short* Kb = (unsigned short*)(ws + NM);   // bf16 [NM]
    unsigned short* Vb = Kb + NM;                 // bf16 [NM]
    float* AT          = ws + 2 * NM;             // fp32 [NM]
    float* H           = ws + 3 * NM;             // fp32 [NM]
    float* S           = ws + 4 * NM;             // fp32 [256]

    (void)hipMemsetAsync(S, 0, 256 * sizeof(float), stream);
    qkv_gemm<<<dim3(32, 2, 3), 256, 0, stream>>>(x, Wq, Wk, Wv, bq, bk, bv, Qb, Kb, Vb, S);
    attn_v5<<<NN, 512, 0, stream>>>(Qb, Kb, Vb, adj, S, AT);
    out_gemm<<<dim3(64, 4), 256, 0, stream>>>(AT, Wo, bo, x, H);
    ln_kernel<<<1024, 256, 0, stream>>>(H, gamma, beta, (float*)d_out);
}